// Round 6
// baseline (588.837 us; speedup 1.0000x reference)
//
#include <hip/hip_runtime.h>
#include <hip/hip_bf16.h>
#include <stdint.h>

// LittleBitLinear: y = [(x*v2) @ sign(V)^T * (v1*u2)] @ sign(U)^T * u1  (x2 branches) + bias
// All inputs FLOAT32, output FLOAT32. Fold scales into binarized weights -> two bf16 GEMMs.
//   Xb  [8192][4096]  bf16 copy of x
//   Wb1 [2048][4096]  bf16 (B^T layout), rows 0..1023 branch1, 1024..2047 branch2
//   H   [8192][2048]  bf16 = Xb @ Wb1^T
//   Wb2 [4096][2048]  bf16 (B^T layout), K-concat of both branches, scaled by u1
//   Y   [8192][4096]  fp32 = H @ Wb2^T + bias
//
// Round 10: round-9's 8-phase schedule lifted MfmaUtil 24->34% but BOTH gemms
// pinned at 166us = 1.07GB staged / 6.45 TB/s -> L3-source-bandwidth-bound
// (only 0.88 TB/s of it is HBM; LDS+MFMA resource math says ~1.6K cy/iter
// achievable vs 12.5K measured -> pipes starved by staging source).
// Fix: L2-RESIDENCY swizzle. Each XCD owns gx/8 whole block-COLUMNS; its 32
// CUs run the same column concurrently -> the column's B panel (2MB gemm1 /
// 1MB gemm2) stays resident in that XCD's 4MB L2 across all its blocks' K-
// sweeps. B staging (0.5GB/dispatch) moves from the L3 path to L2; A row-
// panels are block-unique and stream from L3 once per XCD. L3-sourced bytes
// per GEMM: ~1.0GB -> ~0.55GB.
// Also: convert_x + prep_w1 + prep_w2 fused into one dispatch (2 fewer gaps).
// 8-phase schedule, staging order, vmcnt counts: UNCHANGED from round 9.
// NOTE: LDS dest of global_load_lds must be wave-uniform base + lane*16, and a
// real addrspace(3) cast (no integer truncation).

typedef __bf16 bf16x8 __attribute__((ext_vector_type(8)));
typedef float f32x4 __attribute__((ext_vector_type(4)));

__device__ __forceinline__ void async_copy16(const void* g, void* l) {
  __builtin_amdgcn_global_load_lds(
      (const __attribute__((address_space(1))) uint32_t*)g,
      (__attribute__((address_space(3))) uint32_t*)l,
      16, 0, 0);
}

__device__ __forceinline__ float sgn(float v) {
  return (v > 0.f) ? 1.f : ((v < 0.f) ? -1.f : 0.f);
}

__device__ __forceinline__ void store_out(float* p, float v) { *p = v; }
__device__ __forceinline__ void store_out(__hip_bfloat16* p, float v) { *p = __float2bfloat16(v); }

// ---- fused prep: convert_x (blocks [0,16384)), prep_w1 ([16384,20480)),
// ---- prep_w2 ([20480,24576)). All bodies identical to round 9's kernels.
__global__ __launch_bounds__(256) void prep_all(
    const float* __restrict__ x, __hip_bfloat16* __restrict__ xb,
    const float* __restrict__ V, const float* __restrict__ v2,
    const float* __restrict__ v1, const float* __restrict__ u2,
    const float* __restrict__ V_R, const float* __restrict__ v2_R,
    const float* __restrict__ v1_R, const float* __restrict__ u2_R,
    __hip_bfloat16* __restrict__ W1,
    const float* __restrict__ U, const float* __restrict__ u1,
    const float* __restrict__ U_R, const float* __restrict__ u1_R,
    __hip_bfloat16* __restrict__ W2) {
  const int b = blockIdx.x;
  if (b < 16384) {
    // convert_x: fp32 -> bf16, 8 elements/thread
    int i = (b * 256 + threadIdx.x) * 8;
    const float4* p0 = (const float4*)(x + i);
    float4 a = p0[0], c = p0[1];
    __hip_bfloat16 o[8] = {
        __float2bfloat16(a.x), __float2bfloat16(a.y), __float2bfloat16(a.z), __float2bfloat16(a.w),
        __float2bfloat16(c.x), __float2bfloat16(c.y), __float2bfloat16(c.z), __float2bfloat16(c.w)};
    *(uint4*)(xb + i) = *(const uint4*)o;
  } else if (b < 20480) {
    // prep_w1: W1[s][k] = sign(V[s][k]) * v2[k] * v1[s] * u2[s]
    int g = (b - 16384) * 256 + threadIdx.x;
    int k = (g & 511) * 8;
    int s = g >> 9;
    const float *Vp, *v2p;
    float rs;
    if (s < 1024) {
      Vp = V + s * 4096 + k; v2p = v2 + k; rs = v1[s] * u2[s];
    } else {
      int ss = s - 1024;
      Vp = V_R + ss * 4096 + k; v2p = v2_R + k; rs = v1_R[ss] * u2_R[ss];
    }
    __hip_bfloat16 o[8];
#pragma unroll
    for (int e = 0; e < 8; ++e)
      o[e] = __float2bfloat16(sgn(Vp[e]) * v2p[e] * rs);
    *(uint4*)(W1 + s * 4096 + k) = *(const uint4*)o;
  } else {
    // prep_w2: W2[j][s] = sign(U[j][s]) * u1[j]
    int g = (b - 20480) * 256 + threadIdx.x;
    int s = (g & 255) * 8;
    int j = g >> 8;
    const float* Up;
    float sc;
    if (s < 1024) { Up = U + j * 1024 + s;            sc = u1[j]; }
    else          { Up = U_R + j * 1024 + (s - 1024); sc = u1_R[j]; }
    __hip_bfloat16 o[8];
#pragma unroll
    for (int e = 0; e < 8; ++e)
      o[e] = __float2bfloat16(sgn(Up[e]) * sc);
    *(uint4*)(W2 + j * 2048 + s) = *(const uint4*)o;
  }
}

// One phase: (optional) reload B regs, load 2 A-frags x 2 ksubs, run the STAGE
// statement (stage + optional counted vmcnt), barrier, 16 MFMA under setprio,
// barrier. Q is a literal (compile-time acc indices; rule: no runtime indexing).
#define PHASE(Q, BUF, LOADB, STAGE)                                            \
  {                                                                            \
    if (LOADB) {                                                               \
      _Pragma("unroll") for (int j = 0; j < 4; ++j) {                          \
        bfr[j][0] = ldb(BUF, j, 0);                                            \
        bfr[j][1] = ldb(BUF, j, 1);                                            \
      }                                                                        \
    }                                                                          \
    bf16x8 a00 = lda(BUF, 2 * (Q), 0), a01 = lda(BUF, 2 * (Q), 1);             \
    bf16x8 a10 = lda(BUF, 2 * (Q) + 1, 0), a11 = lda(BUF, 2 * (Q) + 1, 1);     \
    STAGE;                                                                     \
    asm volatile("" ::: "memory");                                             \
    __builtin_amdgcn_s_barrier();                                              \
    asm volatile("" ::: "memory");                                             \
    __builtin_amdgcn_s_setprio(1);                                             \
    _Pragma("unroll") for (int j = 0; j < 4; ++j) {                            \
      acc[2 * (Q)][j] = __builtin_amdgcn_mfma_f32_16x16x32_bf16(               \
          a00, bfr[j][0], acc[2 * (Q)][j], 0, 0, 0);                           \
      acc[2 * (Q)][j] = __builtin_amdgcn_mfma_f32_16x16x32_bf16(               \
          a01, bfr[j][1], acc[2 * (Q)][j], 0, 0, 0);                           \
      acc[2 * (Q) + 1][j] = __builtin_amdgcn_mfma_f32_16x16x32_bf16(           \
          a10, bfr[j][0], acc[2 * (Q) + 1][j], 0, 0, 0);                       \
      acc[2 * (Q) + 1][j] = __builtin_amdgcn_mfma_f32_16x16x32_bf16(           \
          a11, bfr[j][1], acc[2 * (Q) + 1][j], 0, 0, 0);                       \
    }                                                                          \
    __builtin_amdgcn_s_setprio(0);                                             \
    asm volatile("" ::: "memory");                                             \
    __builtin_amdgcn_s_barrier();                                              \
    asm volatile("" ::: "memory");                                             \
  }

// C[M][N] = A[M][K] @ Bt[N][K]^T (+bias), bf16 in, fp32 acc.
// 256x256 tile, BK=64, 8 waves (2Mx4N), per-wave 128x64 = 8x4 frags of 16x16.
// LDS 128KB: buf0 [0,64K) = tiles of even K-index, buf1 [64K,128K) = odd.
// Per buf: A [0,32K) cell(row,chunk) at chunk*4096 + row*16 (chunk = k-octet
// 0..7, row 0..255); B [32K,64K) same with N-rows. Half h = rows h*128..+127.
// Staging a half (16KB): wave w stages chunk w, rows r*64+lane (r=0,1):
// dest = w*4096 + h*2048 + r*1024 + lane*16 (wave-uniform base + lane*16).
template <typename OutT>
__global__ __launch_bounds__(512, 2) void gemm_bt(
    const __hip_bfloat16* __restrict__ A,
    const __hip_bfloat16* __restrict__ Bt,
    OutT* __restrict__ C,
    const float* __restrict__ bias,
    int K, int N) {
  __shared__ char smem[131072];
  const int t = threadIdx.x;
  const int lane = t & 63;
  const int w = t >> 6;
  const int wm = (w >> 2) << 7;   // 0 / 128
  const int wn = (w & 3) << 6;    // 0 / 64 / 128 / 192

  // L2-RESIDENCY swizzle: XCD x owns gx/8 whole block-columns.
  // HW round-robins consecutive original linear ids across XCDs (lin%8 = XCD,
  // validated rounds 1-5 via FETCH deltas). Within an XCD, idx enumerates
  // rows-then-columns, so its 32 concurrent CUs (1 block/CU) all work the
  // SAME column: that column's B panel (2MB gemm1 / 1MB gemm2) is L2-resident
  // while A row-panels (block-unique) stream from L3 once per XCD.
  // Requires gx%8==0 and gy==32 (gemm1 gx=8, gemm2 gx=16; both gy=32).
  const int gx = gridDim.x;
  int lin = blockIdx.y * gx + blockIdx.x;
  const int xcd = lin & 7;
  const int idx = lin >> 3;
  const int cpx = gx >> 3;                    // block-columns per XCD (1 or 2)
  const int col = xcd * cpx + (idx >> 5);     // gy == 32
  const int row = idx & 31;
  const int bm = row << 8;
  const int bn = col << 8;

  const int quad = lane >> 4;
  const int l16 = lane & 15;

  f32x4 acc[8][4] = {};
  bf16x8 bfr[4][2];

  const __hip_bfloat16* gAb = A + bm * K;
  const __hip_bfloat16* gBb = Bt + bn * K;

  auto stageA = [&](int k0, int half, int bufOff) {
#pragma unroll
    for (int r = 0; r < 2; ++r)
      async_copy16(gAb + (half * 128 + r * 64 + lane) * K + k0 + w * 8,
                   smem + bufOff + w * 4096 + half * 2048 + r * 1024 + lane * 16);
  };
  auto stageB = [&](int k0, int half, int bufOff) {
#pragma unroll
    for (int r = 0; r < 2; ++r)
      async_copy16(gBb + (half * 128 + r * 64 + lane) * K + k0 + w * 8,
                   smem + bufOff + 32768 + w * 4096 + half * 2048 + r * 1024 + lane * 16);
  };
  auto lda = [&](int bufOff, int i, int s) -> bf16x8 {
    return *(const bf16x8*)(smem + bufOff + ((s << 2) + quad) * 4096 +
                            ((wm + (i << 4) + l16) << 4));
  };
  auto ldb = [&](int bufOff, int j, int s) -> bf16x8 {
    return *(const bf16x8*)(smem + bufOff + 32768 + ((s << 2) + quad) * 4096 +
                            ((wn + (j << 4) + l16) << 4));
  };

  const int NI = K >> 7;  // K / 128: iterations, 2 K-tiles each

  // Prologue: T0 fully (buf0) + T1.B (buf1); T1.A comes at p1-p2 of iter 0.
  stageA(0, 0, 0);
  stageA(0, 1, 0);
  stageB(0, 0, 0);
  stageB(0, 1, 0);
  stageB(64, 0, 65536);
  stageB(64, 1, 65536);
  asm volatile("s_waitcnt vmcnt(4)" ::: "memory");  // T0 landed; T1.B may fly
  __builtin_amdgcn_s_barrier();
  asm volatile("" ::: "memory");

  for (int i = 0; i < NI; ++i) {
    const int kT = i << 7;           // K-offset of tile T = 2i
    const bool full = (i + 1 < NI);  // stage T+2 / T+3 ?
    // ---- K-tile T (buf0), phases 1-4 ----
    PHASE(0, 0, true,  { stageA(kT + 64, 0, 65536); })
    PHASE(1, 0, false, { stageA(kT + 64, 1, 65536); })
    PHASE(2, 0, false, { if (full) stageB(kT + 128, 0, 0); })
    PHASE(3, 0, false, {
      if (full) {
        stageB(kT + 128, 1, 0);
        asm volatile("s_waitcnt vmcnt(4)" ::: "memory");  // T+1 data landed
      } else {
        asm volatile("s_waitcnt vmcnt(0)" ::: "memory");  // drain T+1.A
      }
    })
    // ---- K-tile T+1 (buf1), phases 5-8 ----
    PHASE(0, 65536, true,  { if (full) stageA(kT + 128, 0, 0); })
    PHASE(1, 65536, false, { if (full) stageA(kT + 128, 1, 0); })
    PHASE(2, 65536, false, { if (full) stageB(kT + 192, 0, 65536); })
    PHASE(3, 65536, false, {
      if (full) {
        stageB(kT + 192, 1, 65536);
        asm volatile("s_waitcnt vmcnt(4)" ::: "memory");  // T+2 data landed
      }
    })
  }

  // epilogue: C/D layout col=lane&15, row=quad*4+reg
#pragma unroll
  for (int j = 0; j < 4; ++j) {
    int col2 = bn + wn + (j << 4) + l16;
    float bv = bias ? bias[col2] : 0.0f;
#pragma unroll
    for (int i = 0; i < 8; ++i) {
      int row0 = bm + wm + (i << 4) + (quad << 2);
#pragma unroll
      for (int r = 0; r < 4; ++r)
        store_out(&C[(row0 + r) * N + col2], acc[i][j][r] + bv);
    }
  }
}

extern "C" void kernel_launch(void* const* d_in, const int* in_sizes, int n_in,
                              void* d_out, int out_size, void* d_ws, size_t ws_size,
                              hipStream_t stream) {
  const float* x    = (const float*)d_in[0];
  const float* V    = (const float*)d_in[1];
  const float* U    = (const float*)d_in[2];
  const float* v2   = (const float*)d_in[3];
  const float* v1   = (const float*)d_in[4];
  const float* u2   = (const float*)d_in[5];
  const float* u1   = (const float*)d_in[6];
  const float* V_R  = (const float*)d_in[7];
  const float* U_R  = (const float*)d_in[8];
  const float* v2_R = (const float*)d_in[9];
  const float* v1_R = (const float*)d_in[10];
  const float* u2_R = (const float*)d_in[11];
  const float* u1_R = (const float*)d_in[12];
  const float* bias = (const float*)d_in[13];

  __hip_bfloat16* Xb  = (__hip_bfloat16*)d_ws;          // 8192*4096
  __hip_bfloat16* Wb1 = Xb + 8192 * 4096;               // 2048*4096
  __hip_bfloat16* Wb2 = Wb1 + 2048 * 4096;              // 4096*2048
  float* Y = (float*)d_out;
  __hip_bfloat16* H   = Wb2 + 4096 * 2048;              // 8192*2048

  // fused convert_x + prep_w1 + prep_w2 (one dispatch, disjoint outputs)
  prep_all<<<24576, 256, 0, stream>>>(x, Xb, V, v2, v1, u2, V_R, v2_R, v1_R,
                                      u2_R, Wb1, U, u1, U_R, u1_R, Wb2);

  // H[8192][2048] = Xb @ Wb1^T   (grid 8x32 = 256 blocks = 1/CU, NI=32)
  gemm_bt<__hip_bfloat16><<<dim3(2048 / 256, 8192 / 256), 512, 0, stream>>>(
      Xb, Wb1, H, nullptr, 4096, 2048);
  // Y[8192][4096] = H @ Wb2^T + bias   (grid 16x32 = 512 blocks, NI=16)
  gemm_bt<float><<<dim3(4096 / 256, 8192 / 256), 512, 0, stream>>>(
      H, Wb2, Y, bias, 2048, 4096);
}